// Round 4
// baseline (610.748 us; speedup 1.0000x reference)
//
#include <hip/hip_runtime.h>
#include <hip/hip_bf16.h>

// DynamicBlockSparseMoE: top-4-of-16 expert block-sparse MoE.
// colsum+cvt fused -> gate top4 -> gather w -> GEMM1 -> gather agg -> GEMM2(+bias).
// GEMMs: 256x256, BK=64, 8 waves, 8-phase counted-vmcnt, branch-free steady loop,
// 32x32x16 bf16 MFMA (2495 TF ceiling vs 2075 for 16x16x32).

#define BATCH 4096
#define DIN 4096
#define NE 16
#define HD 1024
#define TOPK 4
#define TOTC (NE * HD)
#define NT 64

using bf16 = __hip_bfloat16;
typedef __attribute__((ext_vector_type(8))) short short8;
typedef __attribute__((ext_vector_type(4))) float f32x4;
typedef __attribute__((ext_vector_type(16))) float f32x16;

__device__ inline short f2bs(float f) {
  __hip_bfloat16 h = __float2bfloat16(f);
  return *reinterpret_cast<short*>(&h);
}

// ---- fused column-sum + bf16 convert --------------------------------------
__global__ void k_cvtsum(const float* __restrict__ x, bf16* __restrict__ xb,
                         float* __restrict__ pcol) {
  const int lane = threadIdx.x & 63;
  const int w = threadIdx.x >> 6;  // 0..3
  const int c = blockIdx.x * 256 + lane * 4;
  const int r0 = blockIdx.y * 128 + w * 32;
  float4 s = {0.f, 0.f, 0.f, 0.f};
  for (int i = 0; i < 32; ++i) {
    size_t off = (size_t)(r0 + i) * DIN + c;
    float4 v = *reinterpret_cast<const float4*>(x + off);
    s.x += v.x; s.y += v.y; s.z += v.z; s.w += v.w;
    ushort4 b;
    b.x = (unsigned short)f2bs(v.x); b.y = (unsigned short)f2bs(v.y);
    b.z = (unsigned short)f2bs(v.z); b.w = (unsigned short)f2bs(v.w);
    *reinterpret_cast<ushort4*>(reinterpret_cast<char*>(xb) + off * 2) = b;
  }
  *reinterpret_cast<float4*>(pcol + (size_t)(blockIdx.y * 4 + w) * DIN + c) = s;
}

__global__ void k_red(const float* __restrict__ pcol, float* __restrict__ colsum) {
  int c = blockIdx.x * 256 + threadIdx.x;
  float s = 0.f;
  for (int j = 0; j < 128; ++j) s += pcol[(size_t)j * DIN + c];
  colsum[c] = s;
}

__global__ void k_gate(const float* __restrict__ colsum, const float* __restrict__ gw,
                       const float* __restrict__ gb, int* __restrict__ ids) {
  __shared__ float red[4][16];
  __shared__ float gs[16];
  int t = threadIdx.x;
  int e = t & 15, kg = t >> 4;
  float p = 0.f;
  for (int k = kg; k < DIN; k += 16) p += colsum[k] * gw[(size_t)k * NE + e];
  p += __shfl_down(p, 32);
  p += __shfl_down(p, 16);
  if ((t & 63) < 16) red[t >> 6][e] = p;
  __syncthreads();
  if (t < 16) gs[t] = red[0][t] + red[1][t] + red[2][t] + red[3][t] + (float)BATCH * gb[t];
  __syncthreads();
  if (t == 0) {
    float v[16];
    #pragma unroll
    for (int i = 0; i < 16; ++i) v[i] = gs[i];
    for (int j = 0; j < TOPK; ++j) {
      int bi = 0;
      float bv = v[0];
      for (int i2 = 1; i2 < 16; ++i2)
        if (v[i2] > bv) { bv = v[i2]; bi = i2; }
      ids[j] = bi;
      v[bi] = -3.4e38f;
    }
  }
}

// ---- gathers: 64x64 tile, float4 loads, pad-65 LDS transpose, short8 writes
__global__ void k_gather_w(const float* __restrict__ w, const int* __restrict__ ids,
                           bf16* __restrict__ wbt) {
  __shared__ float tile[64 * 65];
  const int k0 = (blockIdx.x & 63) * 64;
  const int n0 = (blockIdx.x >> 6) * 64;
  const int t = threadIdx.x;
  const int e = ids[n0 >> 10];
  const int wc0 = e * HD + (n0 & 1023);
  const int tc = t & 15, kr = t >> 4;
  #pragma unroll
  for (int j = 0; j < 4; ++j) {
    int kk = kr + j * 16;
    float4 v = *reinterpret_cast<const float4*>(w + (size_t)(k0 + kk) * TOTC + wc0 + tc * 4);
    float* dst = &tile[kk * 65 + tc * 4];
    dst[0] = v.x; dst[1] = v.y; dst[2] = v.z; dst[3] = v.w;
  }
  __syncthreads();
  const int tk = t & 7, nr0 = t >> 3;
  #pragma unroll
  for (int i = 0; i < 2; ++i) {
    int n = n0 + nr0 + i * 32;
    short8 r;
    #pragma unroll
    for (int m = 0; m < 8; ++m) r[m] = f2bs(tile[(tk * 8 + m) * 65 + nr0 + i * 32]);
    *reinterpret_cast<short8*>(wbt + (size_t)n * DIN + k0 + tk * 8) = r;
  }
}

__global__ void k_gather_a(const float* __restrict__ a, const int* __restrict__ ids,
                           bf16* __restrict__ abt) {
  __shared__ float tile[64 * 65];
  const int k0 = (blockIdx.x & 63) * 64;
  const int n0 = (blockIdx.x >> 6) * 64;
  const int t = threadIdx.x;
  const int e = ids[k0 >> 10];
  const int ar0 = e * HD + (k0 & 1023);
  const int tc = t & 15, kr = t >> 4;
  #pragma unroll
  for (int j = 0; j < 4; ++j) {
    int kk = kr + j * 16;
    float4 v = *reinterpret_cast<const float4*>(a + (size_t)(ar0 + kk) * 4096 + n0 + tc * 4);
    float* dst = &tile[kk * 65 + tc * 4];
    dst[0] = v.x; dst[1] = v.y; dst[2] = v.z; dst[3] = v.w;
  }
  __syncthreads();
  const int tk = t & 7, nr0 = t >> 3;
  #pragma unroll
  for (int i = 0; i < 2; ++i) {
    int n = n0 + nr0 + i * 32;
    short8 r;
    #pragma unroll
    for (int m = 0; m < 8; ++m) r[m] = f2bs(tile[(tk * 8 + m) * 65 + nr0 + i * 32]);
    *reinterpret_cast<short8*>(abt + (size_t)n * DIN + k0 + tk * 8) = r;
  }
}

// ---- GEMM: 256x256 tile, BK=64, 8 waves, 4 phases/K-tile, 32x32x16 MFMA ----
#define MFMA32 __builtin_amdgcn_mfma_f32_32x32x16_bf16
#define VM4 asm volatile("s_waitcnt vmcnt(4)" ::: "memory")
#define VM0 asm volatile("s_waitcnt vmcnt(0)" ::: "memory")
#define NOST ((void)0)

// One phase = one M-frag (32 rows) x all N (2 frags) x full BK (4 k-slices) = 8 MFMA.
#define PH32(BUF, MF, STG, GATE)                                                \
  do {                                                                          \
    if ((MF) == 0) {                                                            \
      _Pragma("unroll") for (int nf = 0; nf < 2; ++nf)                          \
        _Pragma("unroll") for (int ks = 0; ks < 4; ++ks)                        \
          bfrag[nf][ks] = LDB(BUF, nf, ks);                                     \
    }                                                                           \
    short8 af0 = LDA(BUF, MF, 0), af1 = LDA(BUF, MF, 1);                        \
    short8 af2 = LDA(BUF, MF, 2), af3 = LDA(BUF, MF, 3);                        \
    STG;                                                                        \
    GATE;                                                                       \
    __builtin_amdgcn_s_barrier();                                               \
    __builtin_amdgcn_s_setprio(1);                                              \
    acc[MF][0] = MFMA32(af0, bfrag[0][0], acc[MF][0], 0, 0, 0);                 \
    acc[MF][1] = MFMA32(af0, bfrag[1][0], acc[MF][1], 0, 0, 0);                 \
    acc[MF][0] = MFMA32(af1, bfrag[0][1], acc[MF][0], 0, 0, 0);                 \
    acc[MF][1] = MFMA32(af1, bfrag[1][1], acc[MF][1], 0, 0, 0);                 \
    acc[MF][0] = MFMA32(af2, bfrag[0][2], acc[MF][0], 0, 0, 0);                 \
    acc[MF][1] = MFMA32(af2, bfrag[1][2], acc[MF][1], 0, 0, 0);                 \
    acc[MF][0] = MFMA32(af3, bfrag[0][3], acc[MF][0], 0, 0, 0);                 \
    acc[MF][1] = MFMA32(af3, bfrag[1][3], acc[MF][1], 0, 0, 0);                 \
    __builtin_amdgcn_s_setprio(0);                                              \
    __builtin_amdgcn_s_barrier();                                               \
  } while (0)

template <int STORE_F32>
__global__ __launch_bounds__(512, 2) void k_gemm8(
    const bf16* __restrict__ A, const bf16* __restrict__ Bt,
    bf16* __restrict__ Cb, float* __restrict__ Cf, const float* __restrict__ bias) {
  __shared__ __align__(16) char smraw[131072];
  const int t = threadIdx.x;
  const int lane = t & 63;
  const int w = t >> 6;
  const int wr = w >> 2;   // M half (128 rows)
  const int wc = w & 3;    // N quarter (64 cols)

  const int bid = blockIdx.x;
  const int swz = (bid & 7) * 32 + (bid >> 3);
  const int bm = (swz >> 4) * 256;
  const int bn = (swz & 15) * 256;

  f32x16 acc[4][2] = {};     // 4 M-frags x 2 N-frags of 32x32
  short8 bfrag[2][4];        // [nf][ks]

  const int srow = w * 16 + (lane >> 3);
  const int sgr = lane & 7;

  auto STAGE_A = [&](int buf, int half, int kt) {
    char* lb = smraw + buf * 65536 + half * 16384 + w * 2048 + lane * 16;
    #pragma unroll
    for (int i = 0; i < 2; ++i) {
      int r = srow + i * 8;
      const bf16* g = A + (size_t)(bm + half * 128 + r) * 4096 + kt * 64 + ((sgr ^ (r & 7)) * 8);
      __builtin_amdgcn_global_load_lds(
          (const __attribute__((address_space(1))) void*)g,
          (__attribute__((address_space(3))) void*)(lb + i * 1024), 16, 0, 0);
    }
  };
  auto STAGE_B = [&](int buf, int half, int kt) {
    char* lb = smraw + buf * 65536 + 32768 + half * 16384 + w * 2048 + lane * 16;
    #pragma unroll
    for (int i = 0; i < 2; ++i) {
      int r = srow + i * 8;
      const bf16* g = Bt + (size_t)(bn + half * 128 + r) * 4096 + kt * 64 + ((sgr ^ (r & 7)) * 8);
      __builtin_amdgcn_global_load_lds(
          (const __attribute__((address_space(1))) void*)g,
          (__attribute__((address_space(3))) void*)(lb + i * 1024), 16, 0, 0);
    }
  };
  // A-frag for 32x32x16: lane holds A[mf*32 + (lane&31)][ks*16 + (lane>>5)*8 + 0..7]
  auto LDA = [&](int buf, int mf, int ks) -> short8 {
    int r = mf * 32 + (lane & 31);
    int g = (ks * 2 + (lane >> 5)) ^ (r & 7);
    return *reinterpret_cast<const short8*>(smraw + buf * 65536 + wr * 16384 + r * 128 + g * 16);
  };
  // B-frag: lane holds Bt[nc][ks*16 + (lane>>5)*8 + 0..7], nc = wc*64 + nf*32 + (lane&31)
  auto LDB = [&](int buf, int nf, int ks) -> short8 {
    int nc = wc * 64 + nf * 32 + (lane & 31);
    int half = nc >> 7, r = nc & 127;
    int g = (ks * 2 + (lane >> 5)) ^ (r & 7);
    return *reinterpret_cast<const short8*>(smraw + buf * 65536 + 32768 + half * 16384 + r * 128 + g * 16);
  };

  // Prologue: B(0), A(0) -> buf0; B(1) -> buf1. Complete oldest 8 (B0,A0).
  STAGE_B(0, 0, 0); STAGE_B(0, 1, 0);
  STAGE_A(0, 0, 0); STAGE_A(0, 1, 0);
  STAGE_B(1, 0, 1); STAGE_B(1, 1, 1);
  VM4;
  __builtin_amdgcn_s_barrier();

  // Steady: tiles a=2t (buf0), a+1 (buf1); stages A(a+1), B(a+2), A(a+2), B(a+3).
  for (int tt = 0; tt < 31; ++tt) {
    const int a = 2 * tt;
    PH32(0, 0, STAGE_A(1, 0, a + 1), NOST);
    PH32(0, 1, STAGE_A(1, 1, a + 1), NOST);
    PH32(0, 2, STAGE_B(0, 0, a + 2), NOST);
    PH32(0, 3, STAGE_B(0, 1, a + 2), VM4);
    PH32(1, 0, STAGE_A(0, 0, a + 2), NOST);
    PH32(1, 1, STAGE_A(0, 1, a + 2), NOST);
    PH32(1, 2, STAGE_B(1, 0, a + 3), NOST);
    PH32(1, 3, STAGE_B(1, 1, a + 3), VM4);
  }
  // Tail: tiles 62 (buf0), 63 (buf1).
  PH32(0, 0, STAGE_A(1, 0, 63), NOST);
  PH32(0, 1, STAGE_A(1, 1, 63), NOST);
  PH32(0, 2, NOST, NOST);
  PH32(0, 3, NOST, VM0);
  PH32(1, 0, NOST, NOST);
  PH32(1, 1, NOST, NOST);
  PH32(1, 2, NOST, NOST);
  PH32(1, 3, NOST, NOST);

  // Epilogue: 32x32 C/D layout: col = lane&31, row = (reg&3) + 8*(reg>>2) + 4*(lane>>5).
  #pragma unroll
  for (int mf = 0; mf < 4; ++mf) {
    #pragma unroll
    for (int nf = 0; nf < 2; ++nf) {
      int col = bn + wc * 64 + nf * 32 + (lane & 31);
      int rbase = bm + wr * 128 + mf * 32 + 4 * (lane >> 5);
      float b = STORE_F32 ? bias[col] : 0.f;
      #pragma unroll
      for (int reg = 0; reg < 16; ++reg) {
        int row = rbase + (reg & 3) + 8 * (reg >> 2);
        if constexpr (STORE_F32) {
          Cf[(size_t)row * 4096 + col] = acc[mf][nf][reg] + b;
        } else {
          Cb[(size_t)row * 4096 + col] = __float2bfloat16(acc[mf][nf][reg]);
        }
      }
    }
  }
}

// ---- launch ----------------------------------------------------------------
extern "C" void kernel_launch(void* const* d_in, const int* in_sizes, int n_in,
                              void* d_out, int out_size, void* d_ws, size_t ws_size,
                              hipStream_t stream) {
  const float* x = (const float*)d_in[0];
  const float* gate_w = (const float*)d_in[1];
  const float* gate_b = (const float*)d_in[2];
  const float* weight = (const float*)d_in[3];
  const float* agg_w = (const float*)d_in[4];
  const float* agg_b = (const float*)d_in[5];
  float* out = (float*)d_out;
  char* ws = (char*)d_ws;

  // ws: pcol 2MB @0 | colsum 16KB @2MB | ids @2MB+16KB | mid 32MB @4MB | abt 32MB @36MB
  float* pcol = (float*)ws;
  float* colsum = (float*)(ws + (2u << 20));
  int* ids = (int*)(ws + (2u << 20) + 16384);
  bf16* mid = (bf16*)(ws + (4u << 20));
  bf16* abt = (bf16*)(ws + (36u << 20));
  // scratch inside d_out (dead before GEMM2 writes it):
  bf16* xb = (bf16*)d_out;
  bf16* wbt = (bf16*)((char*)d_out + (32u << 20));

  k_cvtsum<<<dim3(16, 32), 256, 0, stream>>>(x, xb, pcol);
  k_red<<<16, 256, 0, stream>>>(pcol, colsum);
  k_gate<<<1, 256, 0, stream>>>(colsum, gate_w, gate_b, ids);
  k_gather_w<<<4096, 256, 0, stream>>>(weight, ids, wbt);
  k_gemm8<0><<<256, 512, 0, stream>>>(xb, wbt, mid, nullptr, nullptr);
  k_gather_a<<<4096, 256, 0, stream>>>(agg_w, ids, abt);
  k_gemm8<1><<<256, 512, 0, stream>>>(mid, abt, nullptr, out, agg_b);
}

// Round 5
// 393.765 us; speedup vs baseline: 1.5510x; 1.5510x over previous
//
#include <hip/hip_runtime.h>
#include <hip/hip_bf16.h>

// DynamicBlockSparseMoE: top-4-of-16 expert block-sparse MoE.
// colsum+cvt fused -> gate top4 -> gather w -> GEMM1 -> gather agg -> GEMM2(+bias).
// GEMMs: 256x256, BK=64, 8 waves, 16x16x32 MFMA, 2 phases/K-tile (32 MFMA each),
// counted vmcnt(4) once per tile, branch-free steady loop.

#define BATCH 4096
#define DIN 4096
#define NE 16
#define HD 1024
#define TOPK 4
#define TOTC (NE * HD)
#define NT 64

using bf16 = __hip_bfloat16;
typedef __attribute__((ext_vector_type(8))) short short8;
typedef __attribute__((ext_vector_type(4))) float f32x4;

__device__ inline short f2bs(float f) {
  __hip_bfloat16 h = __float2bfloat16(f);
  return *reinterpret_cast<short*>(&h);
}

// ---- fused column-sum + bf16 convert --------------------------------------
__global__ void k_cvtsum(const float* __restrict__ x, bf16* __restrict__ xb,
                         float* __restrict__ pcol) {
  const int lane = threadIdx.x & 63;
  const int w = threadIdx.x >> 6;  // 0..3
  const int c = blockIdx.x * 256 + lane * 4;
  const int r0 = blockIdx.y * 128 + w * 32;
  float4 s = {0.f, 0.f, 0.f, 0.f};
  for (int i = 0; i < 32; ++i) {
    size_t off = (size_t)(r0 + i) * DIN + c;
    float4 v = *reinterpret_cast<const float4*>(x + off);
    s.x += v.x; s.y += v.y; s.z += v.z; s.w += v.w;
    ushort4 b;
    b.x = (unsigned short)f2bs(v.x); b.y = (unsigned short)f2bs(v.y);
    b.z = (unsigned short)f2bs(v.z); b.w = (unsigned short)f2bs(v.w);
    *reinterpret_cast<ushort4*>(reinterpret_cast<char*>(xb) + off * 2) = b;
  }
  *reinterpret_cast<float4*>(pcol + (size_t)(blockIdx.y * 4 + w) * DIN + c) = s;
}

__global__ void k_red(const float* __restrict__ pcol, float* __restrict__ colsum) {
  int c = blockIdx.x * 256 + threadIdx.x;
  float s = 0.f;
  for (int j = 0; j < 128; ++j) s += pcol[(size_t)j * DIN + c];
  colsum[c] = s;
}

__global__ void k_gate(const float* __restrict__ colsum, const float* __restrict__ gw,
                       const float* __restrict__ gb, int* __restrict__ ids) {
  __shared__ float red[4][16];
  __shared__ float gs[16];
  int t = threadIdx.x;
  int e = t & 15, kg = t >> 4;
  float p = 0.f;
  for (int k = kg; k < DIN; k += 16) p += colsum[k] * gw[(size_t)k * NE + e];
  p += __shfl_down(p, 32);
  p += __shfl_down(p, 16);
  if ((t & 63) < 16) red[t >> 6][e] = p;
  __syncthreads();
  if (t < 16) gs[t] = red[0][t] + red[1][t] + red[2][t] + red[3][t] + (float)BATCH * gb[t];
  __syncthreads();
  if (t == 0) {
    float v[16];
    #pragma unroll
    for (int i = 0; i < 16; ++i) v[i] = gs[i];
    for (int j = 0; j < TOPK; ++j) {
      int bi = 0;
      float bv = v[0];
      for (int i2 = 1; i2 < 16; ++i2)
        if (v[i2] > bv) { bv = v[i2]; bi = i2; }
      ids[j] = bi;
      v[bi] = -3.4e38f;
    }
  }
}

// ---- gathers: 64x64 tile, float4 loads, pad-65 LDS transpose, short8 writes
__global__ void k_gather_w(const float* __restrict__ w, const int* __restrict__ ids,
                           bf16* __restrict__ wbt) {
  __shared__ float tile[64 * 65];
  const int k0 = (blockIdx.x & 63) * 64;
  const int n0 = (blockIdx.x >> 6) * 64;
  const int t = threadIdx.x;
  const int e = ids[n0 >> 10];
  const int wc0 = e * HD + (n0 & 1023);
  const int tc = t & 15, kr = t >> 4;
  #pragma unroll
  for (int j = 0; j < 4; ++j) {
    int kk = kr + j * 16;
    float4 v = *reinterpret_cast<const float4*>(w + (size_t)(k0 + kk) * TOTC + wc0 + tc * 4);
    float* dst = &tile[kk * 65 + tc * 4];
    dst[0] = v.x; dst[1] = v.y; dst[2] = v.z; dst[3] = v.w;
  }
  __syncthreads();
  const int tk = t & 7, nr0 = t >> 3;
  #pragma unroll
  for (int i = 0; i < 2; ++i) {
    int n = n0 + nr0 + i * 32;
    short8 r;
    #pragma unroll
    for (int m = 0; m < 8; ++m) r[m] = f2bs(tile[(tk * 8 + m) * 65 + nr0 + i * 32]);
    *reinterpret_cast<short8*>(wbt + (size_t)n * DIN + k0 + tk * 8) = r;
  }
}

__global__ void k_gather_a(const float* __restrict__ a, const int* __restrict__ ids,
                           bf16* __restrict__ abt) {
  __shared__ float tile[64 * 65];
  const int k0 = (blockIdx.x & 63) * 64;
  const int n0 = (blockIdx.x >> 6) * 64;
  const int t = threadIdx.x;
  const int e = ids[k0 >> 10];
  const int ar0 = e * HD + (k0 & 1023);
  const int tc = t & 15, kr = t >> 4;
  #pragma unroll
  for (int j = 0; j < 4; ++j) {
    int kk = kr + j * 16;
    float4 v = *reinterpret_cast<const float4*>(a + (size_t)(ar0 + kk) * 4096 + n0 + tc * 4);
    float* dst = &tile[kk * 65 + tc * 4];
    dst[0] = v.x; dst[1] = v.y; dst[2] = v.z; dst[3] = v.w;
  }
  __syncthreads();
  const int tk = t & 7, nr0 = t >> 3;
  #pragma unroll
  for (int i = 0; i < 2; ++i) {
    int n = n0 + nr0 + i * 32;
    short8 r;
    #pragma unroll
    for (int m = 0; m < 8; ++m) r[m] = f2bs(tile[(tk * 8 + m) * 65 + nr0 + i * 32]);
    *reinterpret_cast<short8*>(abt + (size_t)n * DIN + k0 + tk * 8) = r;
  }
}

// ---- GEMM: 256x256 tile, BK=64, 8 waves, 2 phases/K-tile, 16x16x32 MFMA ----
#define MFMA_BF16 __builtin_amdgcn_mfma_f32_16x16x32_bf16
#define VM4 asm volatile("s_waitcnt vmcnt(4)" ::: "memory")
#define VM0 asm volatile("s_waitcnt vmcnt(0)" ::: "memory")
#define NOST ((void)0)

// Phase A: reads all 8 B-frags + A mf0-3 (16 ds_read_b128), 32 MFMA (mf0-3).
#define PHA(BUF, STG, GATE)                                                     \
  do {                                                                          \
    _Pragma("unroll") for (int nf = 0; nf < 4; ++nf) {                          \
      bfrag[nf][0] = LDB(BUF, nf, 0);                                           \
      bfrag[nf][1] = LDB(BUF, nf, 1);                                           \
    }                                                                           \
    short8 af[4][2];                                                            \
    _Pragma("unroll") for (int m = 0; m < 4; ++m) {                             \
      af[m][0] = LDA(BUF, m, 0);                                                \
      af[m][1] = LDA(BUF, m, 1);                                                \
    }                                                                           \
    STG;                                                                        \
    GATE;                                                                       \
    __builtin_amdgcn_s_barrier();                                               \
    __builtin_amdgcn_s_setprio(1);                                              \
    _Pragma("unroll") for (int kk = 0; kk < 2; ++kk)                            \
      _Pragma("unroll") for (int m = 0; m < 4; ++m)                             \
        _Pragma("unroll") for (int nf = 0; nf < 4; ++nf)                        \
          acc[m][nf] = MFMA_BF16(af[m][kk], bfrag[nf][kk], acc[m][nf], 0, 0, 0); \
    __builtin_amdgcn_s_setprio(0);                                              \
    __builtin_amdgcn_s_barrier();                                               \
  } while (0)

// Phase B: reads A mf4-7 (8 ds_read_b128), 32 MFMA (mf4-7). bfrag reused.
#define PHB(BUF, STG, GATE)                                                     \
  do {                                                                          \
    short8 af[4][2];                                                            \
    _Pragma("unroll") for (int m = 0; m < 4; ++m) {                             \
      af[m][0] = LDA(BUF, m + 4, 0);                                            \
      af[m][1] = LDA(BUF, m + 4, 1);                                            \
    }                                                                           \
    STG;                                                                        \
    GATE;                                                                       \
    __builtin_amdgcn_s_barrier();                                               \
    __builtin_amdgcn_s_setprio(1);                                              \
    _Pragma("unroll") for (int kk = 0; kk < 2; ++kk)                            \
      _Pragma("unroll") for (int m = 0; m < 4; ++m)                             \
        _Pragma("unroll") for (int nf = 0; nf < 4; ++nf)                        \
          acc[m + 4][nf] = MFMA_BF16(af[m][kk], bfrag[nf][kk], acc[m + 4][nf], 0, 0, 0); \
    __builtin_amdgcn_s_setprio(0);                                              \
    __builtin_amdgcn_s_barrier();                                               \
  } while (0)

template <int STORE_F32>
__global__ __launch_bounds__(512, 2) void k_gemm8(
    const bf16* __restrict__ A, const bf16* __restrict__ Bt,
    bf16* __restrict__ Cb, float* __restrict__ Cf, const float* __restrict__ bias) {
  __shared__ __align__(16) char smraw[131072];
  const int t = threadIdx.x;
  const int lane = t & 63;
  const int w = t >> 6;
  const int wr = w >> 2;   // M half (128 rows)
  const int wc = w & 3;    // N quarter (64 cols)

  const int bid = blockIdx.x;
  const int swz = (bid & 7) * 32 + (bid >> 3);
  const int bm = (swz >> 4) * 256;
  const int bn = (swz & 15) * 256;

  f32x4 acc[8][4] = {};
  short8 bfrag[4][2];

  const int srow = w * 16 + (lane >> 3);
  const int sgr = lane & 7;

  // Stage both halves of A (or B) for K-tile kt into buf: 4 global_load_lds.
  auto STAGE_A = [&](int buf, int kt) {
    #pragma unroll
    for (int half = 0; half < 2; ++half) {
      char* lb = smraw + buf * 65536 + half * 16384 + w * 2048 + lane * 16;
      #pragma unroll
      for (int i = 0; i < 2; ++i) {
        int r = srow + i * 8;
        const bf16* g = A + (size_t)(bm + half * 128 + r) * 4096 + kt * 64 + ((sgr ^ (r & 7)) * 8);
        __builtin_amdgcn_global_load_lds(
            (const __attribute__((address_space(1))) void*)g,
            (__attribute__((address_space(3))) void*)(lb + i * 1024), 16, 0, 0);
      }
    }
  };
  auto STAGE_B = [&](int buf, int kt) {
    #pragma unroll
    for (int half = 0; half < 2; ++half) {
      char* lb = smraw + buf * 65536 + 32768 + half * 16384 + w * 2048 + lane * 16;
      #pragma unroll
      for (int i = 0; i < 2; ++i) {
        int r = srow + i * 8;
        const bf16* g = Bt + (size_t)(bn + half * 128 + r) * 4096 + kt * 64 + ((sgr ^ (r & 7)) * 8);
        __builtin_amdgcn_global_load_lds(
            (const __attribute__((address_space(1))) void*)g,
            (__attribute__((address_space(3))) void*)(lb + i * 1024), 16, 0, 0);
      }
    }
  };
  auto LDA = [&](int buf, int mf, int kk) -> short8 {
    int r = mf * 16 + (lane & 15);
    int kb = ((kk * 4 + (lane >> 4)) ^ (r & 7)) * 16;
    return *reinterpret_cast<const short8*>(smraw + buf * 65536 + wr * 16384 + r * 128 + kb);
  };
  auto LDB = [&](int buf, int nf, int kk) -> short8 {
    int nc = wc * 64 + nf * 16 + (lane & 15);
    int half = nc >> 7, r = nc & 127;
    int kb = ((kk * 4 + (lane >> 4)) ^ (r & 7)) * 16;
    return *reinterpret_cast<const short8*>(smraw + buf * 65536 + 32768 + half * 16384 + r * 128 + kb);
  };

  // Prologue: B(0),A(0) -> buf0; B(1) -> buf1 (12 loads). Complete B0,A0.
  STAGE_B(0, 0);
  STAGE_A(0, 0);
  STAGE_B(1, 1);
  VM4;
  __builtin_amdgcn_s_barrier();

  // Steady: tile a (buf0): stage A(a+1)->buf1, B(a+2)->buf0, gate vmcnt(4);
  //         tile a+1 (buf1): stage A(a+2)->buf0, B(a+3)->buf1, gate vmcnt(4).
  for (int tt = 0; tt < 31; ++tt) {
    const int a = 2 * tt;
    PHA(0, STAGE_A(1, a + 1), NOST);
    PHB(0, STAGE_B(0, a + 2), VM4);
    PHA(1, STAGE_A(0, a + 2), NOST);
    PHB(1, STAGE_B(1, a + 3), VM4);
  }
  // Tail: tile 62 (buf0): stage A(63); drain. Tile 63 (buf1): compute only.
  PHA(0, STAGE_A(1, 63), NOST);
  PHB(0, NOST, VM0);
  PHA(1, NOST, NOST);
  PHB(1, NOST, NOST);

  const int cr = (lane >> 4) * 4;
  const int cc = lane & 15;
  #pragma unroll
  for (int mf = 0; mf < 8; ++mf) {
    #pragma unroll
    for (int nf = 0; nf < 4; ++nf) {
      int row = bm + wr * 128 + mf * 16 + cr;
      int col = bn + wc * 64 + nf * 16 + cc;
      #pragma unroll
      for (int r = 0; r < 4; ++r) {
        if constexpr (STORE_F32) {
          Cf[(size_t)(row + r) * 4096 + col] = acc[mf][nf][r] + bias[col];
        } else {
          Cb[(size_t)(row + r) * 4096 + col] = __float2bfloat16(acc[mf][nf][r]);
        }
      }
    }
  }
}

// ---- launch ----------------------------------------------------------------
extern "C" void kernel_launch(void* const* d_in, const int* in_sizes, int n_in,
                              void* d_out, int out_size, void* d_ws, size_t ws_size,
                              hipStream_t stream) {
  const float* x = (const float*)d_in[0];
  const float* gate_w = (const float*)d_in[1];
  const float* gate_b = (const float*)d_in[2];
  const float* weight = (const float*)d_in[3];
  const float* agg_w = (const float*)d_in[4];
  const float* agg_b = (const float*)d_in[5];
  float* out = (float*)d_out;
  char* ws = (char*)d_ws;

  // ws: pcol 2MB @0 | colsum 16KB @2MB | ids @2MB+16KB | mid 32MB @4MB | abt 32MB @36MB
  float* pcol = (float*)ws;
  float* colsum = (float*)(ws + (2u << 20));
  int* ids = (int*)(ws + (2u << 20) + 16384);
  bf16* mid = (bf16*)(ws + (4u << 20));
  bf16* abt = (bf16*)(ws + (36u << 20));
  // scratch inside d_out (dead before GEMM2 writes it):
  bf16* xb = (bf16*)d_out;
  bf16* wbt = (bf16*)((char*)d_out + (32u << 20));

  k_cvtsum<<<dim3(16, 32), 256, 0, stream>>>(x, xb, pcol);
  k_red<<<16, 256, 0, stream>>>(pcol, colsum);
  k_gate<<<1, 256, 0, stream>>>(colsum, gate_w, gate_b, ids);
  k_gather_w<<<4096, 256, 0, stream>>>(weight, ids, wbt);
  k_gemm8<0><<<256, 512, 0, stream>>>(xb, wbt, mid, nullptr, nullptr);
  k_gather_a<<<4096, 256, 0, stream>>>(agg_w, ids, abt);
  k_gemm8<1><<<256, 512, 0, stream>>>(mid, abt, nullptr, out, agg_b);
}

// Round 6
// 386.360 us; speedup vs baseline: 1.5808x; 1.0192x over previous
//
#include <hip/hip_runtime.h>
#include <hip/hip_bf16.h>

// DynamicBlockSparseMoE: top-4-of-16 expert block-sparse MoE.
// colsum+cvt fused -> gate top4 -> gather w -> GEMM1 -> gather agg -> GEMM2(+bias).
// GEMMs: 256x256, BK=64, 8 waves, 16x16x32 MFMA, 4 phases/K-tile with
// sched_barrier-pinned ds_read issue (m201 anatomy), counted vmcnt.

#define BATCH 4096
#define DIN 4096
#define NE 16
#define HD 1024
#define TOPK 4
#define TOTC (NE * HD)
#define NT 64

using bf16 = __hip_bfloat16;
typedef __attribute__((ext_vector_type(8))) short short8;
typedef __attribute__((ext_vector_type(4))) float f32x4;

__device__ inline short f2bs(float f) {
  __hip_bfloat16 h = __float2bfloat16(f);
  return *reinterpret_cast<short*>(&h);
}

// ---- fused column-sum + bf16 convert --------------------------------------
__global__ void k_cvtsum(const float* __restrict__ x, bf16* __restrict__ xb,
                         float* __restrict__ pcol) {
  const int lane = threadIdx.x & 63;
  const int w = threadIdx.x >> 6;  // 0..3
  const int c = blockIdx.x * 256 + lane * 4;
  const int r0 = blockIdx.y * 128 + w * 32;
  float4 s = {0.f, 0.f, 0.f, 0.f};
  for (int i = 0; i < 32; ++i) {
    size_t off = (size_t)(r0 + i) * DIN + c;
    float4 v = *reinterpret_cast<const float4*>(x + off);
    s.x += v.x; s.y += v.y; s.z += v.z; s.w += v.w;
    ushort4 b;
    b.x = (unsigned short)f2bs(v.x); b.y = (unsigned short)f2bs(v.y);
    b.z = (unsigned short)f2bs(v.z); b.w = (unsigned short)f2bs(v.w);
    *reinterpret_cast<ushort4*>(reinterpret_cast<char*>(xb) + off * 2) = b;
  }
  *reinterpret_cast<float4*>(pcol + (size_t)(blockIdx.y * 4 + w) * DIN + c) = s;
}

__global__ void k_red(const float* __restrict__ pcol, float* __restrict__ colsum) {
  int c = blockIdx.x * 256 + threadIdx.x;
  float s = 0.f;
  for (int j = 0; j < 128; ++j) s += pcol[(size_t)j * DIN + c];
  colsum[c] = s;
}

__global__ void k_gate(const float* __restrict__ colsum, const float* __restrict__ gw,
                       const float* __restrict__ gb, int* __restrict__ ids) {
  __shared__ float red[4][16];
  __shared__ float gs[16];
  int t = threadIdx.x;
  int e = t & 15, kg = t >> 4;
  float p = 0.f;
  for (int k = kg; k < DIN; k += 16) p += colsum[k] * gw[(size_t)k * NE + e];
  p += __shfl_down(p, 32);
  p += __shfl_down(p, 16);
  if ((t & 63) < 16) red[t >> 6][e] = p;
  __syncthreads();
  if (t < 16) gs[t] = red[0][t] + red[1][t] + red[2][t] + red[3][t] + (float)BATCH * gb[t];
  __syncthreads();
  if (t == 0) {
    float v[16];
    #pragma unroll
    for (int i = 0; i < 16; ++i) v[i] = gs[i];
    for (int j = 0; j < TOPK; ++j) {
      int bi = 0;
      float bv = v[0];
      for (int i2 = 1; i2 < 16; ++i2)
        if (v[i2] > bv) { bv = v[i2]; bi = i2; }
      ids[j] = bi;
      v[bi] = -3.4e38f;
    }
  }
}

// ---- gathers: 64x64 tile, float4 loads, pad-65 LDS transpose, short8 writes
__global__ void k_gather_w(const float* __restrict__ w, const int* __restrict__ ids,
                           bf16* __restrict__ wbt) {
  __shared__ float tile[64 * 65];
  const int k0 = (blockIdx.x & 63) * 64;
  const int n0 = (blockIdx.x >> 6) * 64;
  const int t = threadIdx.x;
  const int e = ids[n0 >> 10];
  const int wc0 = e * HD + (n0 & 1023);
  const int tc = t & 15, kr = t >> 4;
  #pragma unroll
  for (int j = 0; j < 4; ++j) {
    int kk = kr + j * 16;
    float4 v = *reinterpret_cast<const float4*>(w + (size_t)(k0 + kk) * TOTC + wc0 + tc * 4);
    float* dst = &tile[kk * 65 + tc * 4];
    dst[0] = v.x; dst[1] = v.y; dst[2] = v.z; dst[3] = v.w;
  }
  __syncthreads();
  const int tk = t & 7, nr0 = t >> 3;
  #pragma unroll
  for (int i = 0; i < 2; ++i) {
    int n = n0 + nr0 + i * 32;
    short8 r;
    #pragma unroll
    for (int m = 0; m < 8; ++m) r[m] = f2bs(tile[(tk * 8 + m) * 65 + nr0 + i * 32]);
    *reinterpret_cast<short8*>(wbt + (size_t)n * DIN + k0 + tk * 8) = r;
  }
}

__global__ void k_gather_a(const float* __restrict__ a, const int* __restrict__ ids,
                           bf16* __restrict__ abt) {
  __shared__ float tile[64 * 65];
  const int k0 = (blockIdx.x & 63) * 64;
  const int n0 = (blockIdx.x >> 6) * 64;
  const int t = threadIdx.x;
  const int e = ids[k0 >> 10];
  const int ar0 = e * HD + (k0 & 1023);
  const int tc = t & 15, kr = t >> 4;
  #pragma unroll
  for (int j = 0; j < 4; ++j) {
    int kk = kr + j * 16;
    float4 v = *reinterpret_cast<const float4*>(a + (size_t)(ar0 + kk) * 4096 + n0 + tc * 4);
    float* dst = &tile[kk * 65 + tc * 4];
    dst[0] = v.x; dst[1] = v.y; dst[2] = v.z; dst[3] = v.w;
  }
  __syncthreads();
  const int tk = t & 7, nr0 = t >> 3;
  #pragma unroll
  for (int i = 0; i < 2; ++i) {
    int n = n0 + nr0 + i * 32;
    short8 r;
    #pragma unroll
    for (int m = 0; m < 8; ++m) r[m] = f2bs(tile[(tk * 8 + m) * 65 + nr0 + i * 32]);
    *reinterpret_cast<short8*>(abt + (size_t)n * DIN + k0 + tk * 8) = r;
  }
}

// ---- GEMM: 256x256, BK=64, 8 waves, 4 phases/K-tile, pinned schedule -------
#define MFMA_BF16 __builtin_amdgcn_mfma_f32_16x16x32_bf16
#define VM4 asm volatile("s_waitcnt vmcnt(4)" ::: "memory")
#define VM0 asm volatile("s_waitcnt vmcnt(0)" ::: "memory")
#define NOST ((void)0)

#define PH(BUF, Q, STG, GATE)                                                   \
  do {                                                                          \
    if ((Q) == 0) {                                                             \
      _Pragma("unroll") for (int nf = 0; nf < 4; ++nf) {                        \
        bfrag[nf][0] = LDB(BUF, nf, 0);                                         \
        bfrag[nf][1] = LDB(BUF, nf, 1);                                         \
      }                                                                         \
    }                                                                           \
    short8 aA0 = LDA(BUF, 2 * (Q), 0), aA1 = LDA(BUF, 2 * (Q), 1);              \
    short8 aB0 = LDA(BUF, 2 * (Q) + 1, 0), aB1 = LDA(BUF, 2 * (Q) + 1, 1);      \
    STG;                                                                        \
    GATE;                                                                       \
    __builtin_amdgcn_sched_barrier(0); /* pin: reads+stage issue BEFORE bar */  \
    __builtin_amdgcn_s_barrier();                                               \
    asm volatile("s_waitcnt lgkmcnt(0)" ::: "memory");                          \
    __builtin_amdgcn_sched_barrier(0); /* rule #18: MFMA stays below wait */    \
    __builtin_amdgcn_s_setprio(1);                                              \
    _Pragma("unroll") for (int nf = 0; nf < 4; ++nf) {                          \
      acc[2 * (Q)][nf] = MFMA_BF16(aA0, bfrag[nf][0], acc[2 * (Q)][nf], 0, 0, 0);       \
      acc[2 * (Q)][nf] = MFMA_BF16(aA1, bfrag[nf][1], acc[2 * (Q)][nf], 0, 0, 0);       \
      acc[2 * (Q) + 1][nf] = MFMA_BF16(aB0, bfrag[nf][0], acc[2 * (Q) + 1][nf], 0, 0, 0); \
      acc[2 * (Q) + 1][nf] = MFMA_BF16(aB1, bfrag[nf][1], acc[2 * (Q) + 1][nf], 0, 0, 0); \
    }                                                                           \
    __builtin_amdgcn_s_setprio(0);                                              \
    __builtin_amdgcn_s_barrier();                                               \
  } while (0)

template <int STORE_F32>
__global__ __launch_bounds__(512, 2) void k_gemm8(
    const bf16* __restrict__ A, const bf16* __restrict__ Bt,
    bf16* __restrict__ Cb, float* __restrict__ Cf, const float* __restrict__ bias) {
  __shared__ __align__(16) char smraw[131072];
  const int t = threadIdx.x;
  const int lane = t & 63;
  const int w = t >> 6;
  const int wr = w >> 2;
  const int wc = w & 3;

  const int bid = blockIdx.x;
  const int swz = (bid & 7) * 32 + (bid >> 3);
  const int bm = (swz >> 4) * 256;
  const int bn = (swz & 15) * 256;

  f32x4 acc[8][4] = {};
  short8 bfrag[4][2];

  const int srow = w * 16 + (lane >> 3);
  const int sgr = lane & 7;

  auto STAGE_A = [&](int buf, int half, int kt) {
    char* lb = smraw + buf * 65536 + half * 16384 + w * 2048 + lane * 16;
    #pragma unroll
    for (int i = 0; i < 2; ++i) {
      int r = srow + i * 8;
      const bf16* g = A + (size_t)(bm + half * 128 + r) * 4096 + kt * 64 + ((sgr ^ (r & 7)) * 8);
      __builtin_amdgcn_global_load_lds(
          (const __attribute__((address_space(1))) void*)g,
          (__attribute__((address_space(3))) void*)(lb + i * 1024), 16, 0, 0);
    }
  };
  auto STAGE_B = [&](int buf, int half, int kt) {
    char* lb = smraw + buf * 65536 + 32768 + half * 16384 + w * 2048 + lane * 16;
    #pragma unroll
    for (int i = 0; i < 2; ++i) {
      int r = srow + i * 8;
      const bf16* g = Bt + (size_t)(bn + half * 128 + r) * 4096 + kt * 64 + ((sgr ^ (r & 7)) * 8);
      __builtin_amdgcn_global_load_lds(
          (const __attribute__((address_space(1))) void*)g,
          (__attribute__((address_space(3))) void*)(lb + i * 1024), 16, 0, 0);
    }
  };
  auto LDA = [&](int buf, int mf, int kk) -> short8 {
    int r = mf * 16 + (lane & 15);
    int kb = ((kk * 4 + (lane >> 4)) ^ (r & 7)) * 16;
    return *reinterpret_cast<const short8*>(smraw + buf * 65536 + wr * 16384 + r * 128 + kb);
  };
  auto LDB = [&](int buf, int nf, int kk) -> short8 {
    int nc = wc * 64 + nf * 16 + (lane & 15);
    int half = nc >> 7, r = nc & 127;
    int kb = ((kk * 4 + (lane >> 4)) ^ (r & 7)) * 16;
    return *reinterpret_cast<const short8*>(smraw + buf * 65536 + 32768 + half * 16384 + r * 128 + kb);
  };

  // Prologue: B(0), A(0) -> buf0; B(1) -> buf1. Complete oldest 8 (B0,A0).
  STAGE_B(0, 0, 0); STAGE_B(0, 1, 0);
  STAGE_A(0, 0, 0); STAGE_A(0, 1, 0);
  STAGE_B(1, 0, 1); STAGE_B(1, 1, 1);
  VM4;
  __builtin_amdgcn_s_barrier();

  // Steady: tiles a=2t (buf0), a+1 (buf1); stages A(a+1), B(a+2), A(a+2), B(a+3).
  for (int tt = 0; tt < 31; ++tt) {
    const int a = 2 * tt;
    PH(0, 0, STAGE_A(1, 0, a + 1), NOST);
    PH(0, 1, STAGE_A(1, 1, a + 1), NOST);
    PH(0, 2, STAGE_B(0, 0, a + 2), NOST);
    PH(0, 3, STAGE_B(0, 1, a + 2), VM4);
    PH(1, 0, STAGE_A(0, 0, a + 2), NOST);
    PH(1, 1, STAGE_A(0, 1, a + 2), NOST);
    PH(1, 2, STAGE_B(1, 0, a + 3), NOST);
    PH(1, 3, STAGE_B(1, 1, a + 3), VM4);
  }
  // Tail: tiles 62 (buf0), 63 (buf1). A(63) staged in ph0-1, then drain.
  PH(0, 0, STAGE_A(1, 0, 63), NOST);
  PH(0, 1, STAGE_A(1, 1, 63), NOST);
  PH(0, 2, NOST, NOST);
  PH(0, 3, NOST, VM0);
  PH(1, 0, NOST, NOST);
  PH(1, 1, NOST, NOST);
  PH(1, 2, NOST, NOST);
  PH(1, 3, NOST, NOST);

  const int cr = (lane >> 4) * 4;
  const int cc = lane & 15;
  #pragma unroll
  for (int mf = 0; mf < 8; ++mf) {
    #pragma unroll
    for (int nf = 0; nf < 4; ++nf) {
      int row = bm + wr * 128 + mf * 16 + cr;
      int col = bn + wc * 64 + nf * 16 + cc;
      #pragma unroll
      for (int r = 0; r < 4; ++r) {
        if constexpr (STORE_F32) {
          Cf[(size_t)(row + r) * 4096 + col] = acc[mf][nf][r] + bias[col];
        } else {
          Cb[(size_t)(row + r) * 4096 + col] = __float2bfloat16(acc[mf][nf][r]);
        }
      }
    }
  }
}

// ---- launch ----------------------------------------------------------------
extern "C" void kernel_launch(void* const* d_in, const int* in_sizes, int n_in,
                              void* d_out, int out_size, void* d_ws, size_t ws_size,
                              hipStream_t stream) {
  const float* x = (const float*)d_in[0];
  const float* gate_w = (const float*)d_in[1];
  const float* gate_b = (const float*)d_in[2];
  const float* weight = (const float*)d_in[3];
  const float* agg_w = (const float*)d_in[4];
  const float* agg_b = (const float*)d_in[5];
  float* out = (float*)d_out;
  char* ws = (char*)d_ws;

  // ws: pcol 2MB @0 | colsum 16KB @2MB | ids @2MB+16KB | mid 32MB @4MB | abt 32MB @36MB
  float* pcol = (float*)ws;
  float* colsum = (float*)(ws + (2u << 20));
  int* ids = (int*)(ws + (2u << 20) + 16384);
  bf16* mid = (bf16*)(ws + (4u << 20));
  bf16* abt = (bf16*)(ws + (36u << 20));
  // scratch inside d_out (dead before GEMM2 writes it):
  bf16* xb = (bf16*)d_out;
  bf16* wbt = (bf16*)((char*)d_out + (32u << 20));

  k_cvtsum<<<dim3(16, 32), 256, 0, stream>>>(x, xb, pcol);
  k_red<<<16, 256, 0, stream>>>(pcol, colsum);
  k_gate<<<1, 256, 0, stream>>>(colsum, gate_w, gate_b, ids);
  k_gather_w<<<4096, 256, 0, stream>>>(weight, ids, wbt);
  k_gemm8<0><<<256, 512, 0, stream>>>(xb, wbt, mid, nullptr, nullptr);
  k_gather_a<<<4096, 256, 0, stream>>>(agg_w, ids, abt);
  k_gemm8<1><<<256, 512, 0, stream>>>(mid, abt, nullptr, out, agg_b);
}